// Round 14
// baseline (425.086 us; speedup 1.0000x reference)
//
#include <hip/hip_runtime.h>
#include <math.h>

#define NTOK 8000
#define KCAP 3200
#define BATCH 2
#define DM 256
#define DFF 1024
#define NSL 16            // top-k j-slices
#define JT (NTOK / NSL)   // 500 elements per slice
#define NB32 (KCAP / 32)  // fragment blocks per (batch,head)

typedef __attribute__((ext_vector_type(4))) short s16x4;
typedef __attribute__((ext_vector_type(8))) short s16x8;
typedef __attribute__((ext_vector_type(16))) float f32x16;

#define MFMA_B(a, b, c) __builtin_amdgcn_mfma_f32_32x32x8bf16_1k(a, b, c, 0, 0, 0)
#define MFMA16(a, b, c) __builtin_amdgcn_mfma_f32_32x32x16_bf16(a, b, c, 0, 0, 0)

__device__ __forceinline__ ushort f2bf(float f) {  // RNE float->bf16 bits
  unsigned u = __float_as_uint(f);
  u += 0x7fffu + ((u >> 16) & 1u);
  return (ushort)(u >> 16);
}
__device__ __forceinline__ unsigned cvt_pk_bf16(float lo, float hi) {
  unsigned r;
  asm("v_cvt_pk_bf16_f32 %0, %1, %2" : "=v"(r) : "v"(lo), "v"(hi));
  return r;
}
__device__ __forceinline__ float fast_exp2(float x) {  // 2^x, raw v_exp
  float r;
  asm("v_exp_f32 %0, %1" : "=v"(r) : "v"(x));
  return r;
}
__device__ __forceinline__ float gelu_tanh(float x) {
  const float z = 0.7978845608028654f * (x + 0.044715f * x * x * x);
  return x * (1.0f / (1.0f + __expf(-2.0f * z)));  // == 0.5x(1+tanh(z))
}
__device__ __forceinline__ f32x16 zero16() {
  f32x16 z;
#pragma unroll
  for (int i = 0; i < 16; ++i) z[i] = 0.f;
  return z;
}

// ---- top-k phase A: partial ranks over a 500-element j-slice (16-way split) ----
__global__ __launch_bounds__(256) void topk_partial(const float* __restrict__ sal,
                                                    int* __restrict__ partial) {
  const int b = blockIdx.z, jc = blockIdx.y;
  __shared__ float4 s4[JT / 4];
  const float4* src4 = reinterpret_cast<const float4*>(sal + (size_t)b * NTOK + jc * JT);
  for (int e = threadIdx.x; e < JT / 4; e += 256) s4[e] = src4[e];
  __syncthreads();
  const int i = blockIdx.x * 256 + threadIdx.x;
  if (i >= NTOK) return;
  const float si = sal[(size_t)b * NTOK + i];
  int rank = 0;
  const int jbase = jc * JT;
#pragma unroll 5
  for (int e = 0; e < JT / 4; ++e) {
    const float4 v = s4[e];
    const int j = jbase + e * 4;
    rank += (int)((v.x > si) || (v.x == si && j + 0 < i));
    rank += (int)((v.y > si) || (v.y == si && j + 1 < i));
    rank += (int)((v.z > si) || (v.z == si && j + 2 < i));
    rank += (int)((v.w > si) || (v.w == si && j + 3 < i));
  }
  partial[((size_t)jc * BATCH + b) * NTOK + i] = rank;
}

// ---- top-k phase B: sum partials, scatter rank<KCAP into sorted index list ----
__global__ __launch_bounds__(256) void topk_finalize(const int* __restrict__ partial,
                                                     int* __restrict__ sidx) {
  const int gid = blockIdx.x * 256 + threadIdx.x;
  if (gid >= BATCH * NTOK) return;
  const int b = gid / NTOK, i = gid - b * NTOK;
  int rank = 0;
#pragma unroll
  for (int jc = 0; jc < NSL; ++jc)
    rank += partial[((size_t)jc * BATCH + b) * NTOK + i];
  if (rank < KCAP) sidx[b * KCAP + rank] = i;
}

// ---- weight prep: fp32 W[l][K][N] -> bf16 MFMA K=16-fragment-major ----
// wf[l][g][sg][lane][e] = W[l][sg*16 + (lane>>5)*8 + e][g*32 + (lane&31)], e=0..7
template <int KD, int N, int LKS, int LN32>
__device__ __forceinline__ void wprep_one(const float* __restrict__ src,
                                          ushort* __restrict__ dst, int slot) {
  const int lane = slot & 63;
  const int sg = (slot >> 6) & ((1 << LKS) - 1);
  const int g = (slot >> (6 + LKS)) & ((1 << LN32) - 1);
  const int l = slot >> (6 + LKS + LN32);
  const int n = g * 32 + (lane & 31);
  const int k = sg * 16 + (lane >> 5) * 8;
  const float* s = src + ((size_t)l * KD + k) * N + n;
  union { uint4 q; ushort us[8]; } o;
#pragma unroll
  for (int e = 0; e < 8; ++e) o.us[e] = f2bf(s[(size_t)e * N]);
  *reinterpret_cast<uint4*>(dst + (size_t)slot * 8) = o.q;
}

__global__ __launch_bounds__(256) void wprep_kernel(
    const float* __restrict__ Wq, const float* __restrict__ Wk,
    const float* __restrict__ Wv, const float* __restrict__ Wo,
    const float* __restrict__ W1, const float* __restrict__ W2,
    ushort* __restrict__ wqt, ushort* __restrict__ wkt, ushort* __restrict__ wvt,
    ushort* __restrict__ wot, ushort* __restrict__ w1t, ushort* __restrict__ w2t) {
  const int z = blockIdx.z;
  const int slot = blockIdx.x * 256 + threadIdx.x;
  if (z < 4) {  // 256x256: N32=8, KS16=16 -> 32768 slots
    if (slot >= 4 * 8 * 16 * 64) return;
    const float* src = z == 0 ? Wq : (z == 1 ? Wk : (z == 2 ? Wv : Wo));
    ushort* dst = z == 0 ? wqt : (z == 1 ? wkt : (z == 2 ? wvt : wot));
    wprep_one<256, 256, 4, 3>(src, dst, slot);
  } else if (z == 4) {  // 256x1024: N32=32, KS16=16 -> 131072 slots
    if (slot >= 4 * 32 * 16 * 64) return;
    wprep_one<256, 1024, 4, 5>(W1, w1t, slot);
  } else {  // 1024x256: N32=8, KS16=64 -> 131072 slots
    if (slot >= 4 * 8 * 64 * 64) return;
    wprep_one<1024, 256, 6, 3>(W2, w2t, slot);
  }
}

// ---- gather + LayerNorm1 (layer 0 only): wave per token, writes x (f32) and h ----
__global__ __launch_bounds__(256) void gather_ln_kernel(
    const float* __restrict__ feat, const int* __restrict__ sidx,
    const float* __restrict__ g, const float* __restrict__ bb,
    float* __restrict__ x, ushort* __restrict__ h, int klen) {
  const int w = threadIdx.x >> 6, lane = threadIdx.x & 63;
  const int m = blockIdx.x * 4 + w;
  const int b = m / klen, t = m - b * klen;
  const int tok = sidx[b * KCAP + t];
  const float4 v4 =
      reinterpret_cast<const float4*>(feat + ((size_t)b * NTOK + tok) * DM)[lane];
  reinterpret_cast<float4*>(x + ((size_t)b * KCAP + t) * DM)[lane] = v4;
  float s = v4.x + v4.y + v4.z + v4.w;
#pragma unroll
  for (int off = 1; off < 64; off <<= 1) s += __shfl_xor(s, off);
  const float mu = s * (1.0f / DM);
  const float4 dv = {v4.x - mu, v4.y - mu, v4.z - mu, v4.w - mu};
  float vs = dv.x * dv.x + dv.y * dv.y + dv.z * dv.z + dv.w * dv.w;
#pragma unroll
  for (int off = 1; off < 64; off <<= 1) vs += __shfl_xor(vs, off);
  const float rstd = rsqrtf(vs * (1.0f / DM) + 1e-5f);
  const float4 g4 = reinterpret_cast<const float4*>(g)[lane];
  const float4 b4 = reinterpret_cast<const float4*>(bb)[lane];
  union { unsigned long long u; ushort us[4]; } o;
  o.us[0] = f2bf(dv.x * rstd * g4.x + b4.x);
  o.us[1] = f2bf(dv.y * rstd * g4.y + b4.y);
  o.us[2] = f2bf(dv.z * rstd * g4.z + b4.z);
  o.us[3] = f2bf(dv.w * rstd * g4.w + b4.w);
  reinterpret_cast<unsigned long long*>(h + ((size_t)b * KCAP + t) * DM)[lane] = o.u;
}

// ---- LayerNorm: wave per token, x (f32) -> h (bf16). Used for LN1 (l>=1) and LN2 ----
__global__ __launch_bounds__(256) void ln_kernel(
    const float* __restrict__ x, const float* __restrict__ g,
    const float* __restrict__ bb, ushort* __restrict__ h, int klen) {
  const int w = threadIdx.x >> 6, lane = threadIdx.x & 63;
  const int m = blockIdx.x * 4 + w;
  const int b = m / klen, t = m - b * klen;
  const float4 v4 = reinterpret_cast<const float4*>(x + ((size_t)b * KCAP + t) * DM)[lane];
  float s = v4.x + v4.y + v4.z + v4.w;
#pragma unroll
  for (int off = 1; off < 64; off <<= 1) s += __shfl_xor(s, off);
  const float mu = s * (1.0f / DM);
  const float4 dv = {v4.x - mu, v4.y - mu, v4.z - mu, v4.w - mu};
  float vs = dv.x * dv.x + dv.y * dv.y + dv.z * dv.z + dv.w * dv.w;
#pragma unroll
  for (int off = 1; off < 64; off <<= 1) vs += __shfl_xor(vs, off);
  const float rstd = rsqrtf(vs * (1.0f / DM) + 1e-5f);
  const float4 g4 = reinterpret_cast<const float4*>(g)[lane];
  const float4 b4 = reinterpret_cast<const float4*>(bb)[lane];
  union { unsigned long long u; ushort us[4]; } o;
  o.us[0] = f2bf(dv.x * rstd * g4.x + b4.x);
  o.us[1] = f2bf(dv.y * rstd * g4.y + b4.y);
  o.us[2] = f2bf(dv.z * rstd * g4.z + b4.z);
  o.us[3] = f2bf(dv.w * rstd * g4.w + b4.w);
  reinterpret_cast<unsigned long long*>(h + ((size_t)b * KCAP + t) * DM)[lane] = o.u;
}

// ---- GEMM core: block = 32 rows x 256 cols, wave = 32x64 (2 acc tiles) ----
// A row-major [t][APITCH] bf16 staged to LDS (XOR-swizzled, same tile as before);
// B fragment-major K=16. One K=16 A-frag = two existing u64 quads (base, base+32).
template <int APITCH, int KCHUNKS>
__device__ __forceinline__ void gemm_core(
    const ushort* __restrict__ A, const ushort* __restrict__ wf,
    unsigned long long* lA, int b, int t0, int klen, f32x16& acc0, f32x16& acc1) {
  const int tid = threadIdx.x;
  const int lane = tid & 63, l31 = lane & 31, hi = lane >> 5, w = tid >> 6;
  const int srow = tid >> 5, sl = tid & 31;
  acc0 = zero16();
  acc1 = zero16();
  const ushort* w0 = wf + (size_t)(w * 2) * (KCHUNKS * 8192) + lane * 8;
  const ushort* w1p = w0 + (size_t)KCHUNKS * 8192;
  for (int kc = 0; kc < KCHUNKS; ++kc) {
    if (kc) __syncthreads();
#pragma unroll
    for (int p = 0; p < 4; ++p) {
      const int row = p * 8 + srow;
      const size_t grow = (size_t)(b * KCAP + min(t0 + row, klen - 1));
      union { uint4 q; unsigned long long d[2]; } u;
      u.q = *reinterpret_cast<const uint4*>(A + grow * APITCH + kc * 256 + sl * 8);
      const int rx = row ^ (sl & 15);
      lA[(sl * 2) * 32 + rx] = u.d[0];
      lA[(sl * 2 + 1) * 32 + rx] = u.d[1];
    }
    __syncthreads();
    const ushort* wc0 = w0 + (size_t)kc * 8192;
    const ushort* wc1 = w1p + (size_t)kc * 8192;
#pragma unroll 8
    for (int s = 0; s < 16; ++s) {
      union { unsigned long long d[2]; s16x8 v; } a;
      const int base = (4 * s + 2 * hi) * 32 + (l31 ^ ((2 * s + hi) & 15));
      a.d[0] = lA[base];
      a.d[1] = lA[base + 32];
      const s16x8 b0 = *reinterpret_cast<const s16x8*>(wc0 + s * 512);
      const s16x8 b1 = *reinterpret_cast<const s16x8*>(wc1 + s * 512);
      acc0 = MFMA16(a.v, b0, acc0);
      acc1 = MFMA16(a.v, b1, acc1);
    }
  }
}

// ---- fused Q/K/V projection (blockIdx.y selects q/k/v) ----
// Q pre-scaled by (1/sqrt(32))*log2(e) so attention works in log2 units.
__global__ __launch_bounds__(256) void qkv_kernel(
    const ushort* __restrict__ hb, const ushort* __restrict__ wq,
    const ushort* __restrict__ wk, const ushort* __restrict__ wv,
    ushort* __restrict__ qh, ushort* __restrict__ Kf, ushort* __restrict__ Vf,
    int klen) {
  __shared__ unsigned long long lA[2048];
  const int z = blockIdx.y;
  const ushort* wf = z == 0 ? wq : (z == 1 ? wk : wv);
  const int nrb = (klen + 31) >> 5;
  const int b = blockIdx.x / nrb;
  const int t0 = (blockIdx.x - b * nrb) * 32;
  f32x16 a0, a1;
  gemm_core<256, 1>(hb, wf, lA, b, t0, klen, a0, a1);
  const int lane = threadIdx.x & 63, l31 = lane & 31, hi = lane >> 5;
  const int w = threadIdx.x >> 6;
  const int hi4 = 4 * hi;
#pragma unroll
  for (int blk = 0; blk < 2; ++blk) {
    const f32x16& acc = blk ? a1 : a0;
    const int hh = w * 2 + blk;
    const int bh = b * 8 + hh;
    if (z == 0) {  // Q pre-scaled (log2 units), head layout [bh][t][32]
#pragma unroll
      for (int r = 0; r < 16; ++r) {
        const int gm = t0 + ((r & 3) + 8 * (r >> 2) + hi4);
        if (gm < klen)
          qh[((size_t)bh * KCAP + gm) * 32 + l31] =
              f2bf(acc[r] * (0.17677669529663687f * 1.4426950408889634f));
      }
    } else if (z == 1) {  // K fragment-major (K=8 frags for attention)
#pragma unroll
      for (int r = 0; r < 16; ++r) {
        const int gm = t0 + ((r & 3) + 8 * (r >> 2) + hi4);
        const int kb = gm >> 5, k31 = gm & 31;
        const int dc = l31 >> 3, hi2 = (l31 >> 2) & 1, e = l31 & 3;
        Kf[(((size_t)bh * NB32 + kb) * 4 + dc) * 256 + (hi2 * 32 + k31) * 4 + e] =
            f2bf(acc[r]);
      }
    } else {  // V fragment-major
#pragma unroll
      for (int r = 0; r < 16; ++r) {
        const int gm = t0 + ((r & 3) + 8 * (r >> 2) + hi4);
        const int kb = gm >> 5, k31 = gm & 31;
        const int kc = k31 >> 3, hi2 = (k31 >> 2) & 1, e = k31 & 3;
        Vf[(((size_t)bh * NB32 + kb) * 4 + kc) * 256 + (hi2 * 32 + l31) * 4 + e] =
            f2bf(acc[r]);
      }
    }
  }
}

// ---- residual GEMM: xb += A @ W (used for Wo and W2, in-place accumulate) ----
template <int APITCH, int KCHUNKS>
__global__ __launch_bounds__(256) void resadd_kernel(const ushort* __restrict__ A,
                                                     const ushort* __restrict__ wf,
                                                     float* __restrict__ xb, int klen) {
  __shared__ unsigned long long lA[2048];
  const int nrb = (klen + 31) >> 5;
  const int b = blockIdx.x / nrb;
  const int t0 = (blockIdx.x - b * nrb) * 32;
  f32x16 a0, a1;
  gemm_core<APITCH, KCHUNKS>(A, wf, lA, b, t0, klen, a0, a1);
  const int lane = threadIdx.x & 63, l31 = lane & 31, hi = lane >> 5;
  const int w = threadIdx.x >> 6;
  const int hi4 = 4 * hi;
#pragma unroll
  for (int blk = 0; blk < 2; ++blk) {
    const f32x16& acc = blk ? a1 : a0;
    const int n = w * 64 + blk * 32 + l31;
#pragma unroll
    for (int r = 0; r < 16; ++r) {
      const int gm = t0 + ((r & 3) + 8 * (r >> 2) + hi4);
      if (gm < klen) {
        const size_t off = ((size_t)b * KCAP + gm) * DM + n;
        xb[off] += acc[r];
      }
    }
  }
}

// ---- W1 GEMM: fb = gelu(hb @ W1), blockIdx.y = 256-col group ----
__global__ __launch_bounds__(256) void w1_kernel(const ushort* __restrict__ hb,
                                                 const ushort* __restrict__ w1,
                                                 ushort* __restrict__ fb, int klen) {
  __shared__ unsigned long long lA[2048];
  const int nrb = (klen + 31) >> 5;
  const int b = blockIdx.x / nrb;
  const int t0 = (blockIdx.x - b * nrb) * 32;
  const ushort* wf = w1 + (size_t)blockIdx.y * 65536;
  f32x16 a0, a1;
  gemm_core<256, 1>(hb, wf, lA, b, t0, klen, a0, a1);
  const int lane = threadIdx.x & 63, l31 = lane & 31, hi = lane >> 5;
  const int w = threadIdx.x >> 6;
  const int hi4 = 4 * hi;
#pragma unroll
  for (int blk = 0; blk < 2; ++blk) {
    const f32x16& acc = blk ? a1 : a0;
    const int n = blockIdx.y * 256 + w * 64 + blk * 32 + l31;
#pragma unroll
    for (int r = 0; r < 16; ++r) {
      const int gm = t0 + ((r & 3) + 8 * (r >> 2) + hi4);
      if (gm < klen)
        fb[((size_t)b * KCAP + gm) * DFF + n] = f2bf(gelu_tanh(acc[r]));
    }
  }
}

// ---- flash attention: block = one 32-q tile, 4 waves split keys 4-way ----
// Fixed-base softmax: S accumulator init = -M0 (log2 units); p = 2^s directly.
#define M0 12.0f
__global__ __launch_bounds__(256) void attn_kernel(
    const ushort* __restrict__ Q, const ushort* __restrict__ Kf,
    const ushort* __restrict__ Vf, ushort* __restrict__ O, int klen) {
  const int hh = blockIdx.y, b = blockIdx.z;
  const int bh = b * 8 + hh;
  const int tid = threadIdx.x;
  const int w = tid >> 6, lane = tid & 63, l31 = lane & 31, hi = lane >> 5;
  __shared__ float red[3 * 64 * 17];  // waves 1-3 partials: o[16], l (stride 17)
  const int q0 = blockIdx.x * 32;
  const int qg = min(q0 + l31, klen - 1);
  const ushort* qrow = Q + ((size_t)bh * KCAP + qg) * 32;
  const s16x4 qf0 = *reinterpret_cast<const s16x4*>(qrow + 0 + hi * 4);
  const s16x4 qf1 = *reinterpret_cast<const s16x4*>(qrow + 8 + hi * 4);
  const s16x4 qf2 = *reinterpret_cast<const s16x4*>(qrow + 16 + hi * 4);
  const s16x4 qf3 = *reinterpret_cast<const s16x4*>(qrow + 24 + hi * 4);
  const ushort* kfp = Kf + (size_t)bh * NB32 * 1024 + lane * 4;
  const ushort* vfp = Vf + (size_t)bh * NB32 * 1024 + lane * 4;
  f32x16 oacc = zero16();
  float lrun = 0.f;
  const int nb = (klen + 31) >> 5;
  const int qq = nb >> 2, rr = nb & 3;
  const int kb0 = w * qq + min(w, rr);
  const int kbn = kb0 + qq + (w < rr ? 1 : 0);
  for (int kb = kb0; kb < kbn; ++kb) {
    const ushort* kb_ = kfp + (size_t)kb * 1024;
    const ushort* vb_ = vfp + (size_t)kb * 1024;
    const s16x4 kf0 = *reinterpret_cast<const s16x4*>(kb_ + 0);
    const s16x4 kf1 = *reinterpret_cast<const s16x4*>(kb_ + 256);
    const s16x4 kf2 = *reinterpret_cast<const s16x4*>(kb_ + 512);
    const s16x4 kf3 = *reinterpret_cast<const s16x4*>(kb_ + 768);
    const s16x4 vf0 = *reinterpret_cast<const s16x4*>(vb_ + 0);
    const s16x4 vf1 = *reinterpret_cast<const s16x4*>(vb_ + 256);
    const s16x4 vf2 = *reinterpret_cast<const s16x4*>(vb_ + 512);
    const s16x4 vf3 = *reinterpret_cast<const s16x4*>(vb_ + 768);
    f32x16 s;
#pragma unroll
    for (int r = 0; r < 16; ++r) s[r] = -M0;  // bias folded into accumulator
    s = MFMA_B(kf0, qf0, s);
    s = MFMA_B(kf1, qf1, s);
    s = MFMA_B(kf2, qf2, s);
    s = MFMA_B(kf3, qf3, s);
    if ((kb << 5) + 32 > klen) {  // mask tail keys (pad K zero-filled)
#pragma unroll
      for (int r = 0; r < 16; ++r) {
        const int key = (kb << 5) + (r & 3) + 8 * (r >> 2) + 4 * hi;
        if (key >= klen) s[r] = -1e30f;
      }
    }
    float p[16];
    float ps = 0.f;
#pragma unroll
    for (int r = 0; r < 16; ++r) {
      p[r] = fast_exp2(s[r]);  // p = 2^(S*log2e - M0): exact softmax ratio
      ps += p[r];
    }
    lrun += ps;
    unsigned pw[8];
#pragma unroll
    for (int i = 0; i < 8; ++i) pw[i] = cvt_pk_bf16(p[2 * i], p[2 * i + 1]);
#pragma unroll
    for (int kc = 0; kc < 4; ++kc) {
      union { unsigned u[2]; s16x4 v; } pf;
      pf.u[0] = pw[2 * kc];
      pf.u[1] = pw[2 * kc + 1];
      const s16x4 vf = kc == 0 ? vf0 : (kc == 1 ? vf1 : (kc == 2 ? vf2 : vf3));
      oacc = MFMA_B(vf, pf.v, oacc);  // O^T[d][q]
    }
  }
  // fixed base -> partials merge by plain summation
  if (w) {
    float* myr = red + ((w - 1) * 64 + lane) * 17;
#pragma unroll
    for (int r = 0; r < 16; ++r) myr[r] = oacc[r];
    myr[16] = lrun;
  }
  __syncthreads();
  if (w == 0) {
#pragma unroll
    for (int w2 = 0; w2 < 3; ++w2) {
      const float* pr = red + (w2 * 64 + lane) * 17;
#pragma unroll
      for (int r = 0; r < 16; ++r) oacc[r] += pr[r];
      lrun += pr[16];
    }
    const float ltot = lrun + __shfl_xor(lrun, 32);
    const float inv = 1.0f / ltot;
    if (q0 + l31 < klen) {
      ushort* orow = O + ((size_t)b * KCAP + q0 + l31) * DM + hh * 32;
#pragma unroll
      for (int rq = 0; rq < 4; ++rq) {
        union { unsigned u[2]; unsigned long long u64; } o4;
        o4.u[0] = cvt_pk_bf16(oacc[4 * rq] * inv, oacc[4 * rq + 1] * inv);
        o4.u[1] = cvt_pk_bf16(oacc[4 * rq + 2] * inv, oacc[4 * rq + 3] * inv);
        *reinterpret_cast<unsigned long long*>(orow + 8 * rq + 4 * hi) = o4.u64;
      }
    }
  }
}

// ---- final scatter: feature bank gets each rank's last-updated row ----
__global__ __launch_bounds__(256) void scatter_kernel(
    const float* __restrict__ x, const int* __restrict__ sidx,
    float* __restrict__ feat) {
  const int gid = blockIdx.x * 256 + threadIdx.x;
  const int m = gid >> 6, li = gid & 63;
  const int b = m / KCAP, t = m - b * KCAP;
  const int tok = sidx[b * KCAP + t];
  reinterpret_cast<float4*>(feat + ((size_t)b * NTOK + tok) * DM)[li] =
      reinterpret_cast<const float4*>(x + ((size_t)b * KCAP + t) * DM)[li];
}

extern "C" void kernel_launch(void* const* d_in, const int* in_sizes, int n_in,
                              void* d_out, int out_size, void* d_ws, size_t ws_size,
                              hipStream_t stream) {
  (void)in_sizes; (void)n_in; (void)out_size; (void)ws_size;
  const float* features = (const float*)d_in[0];
  const float* salience = (const float*)d_in[1];
  const float* Wq = (const float*)d_in[2];
  const float* Wk = (const float*)d_in[3];
  const float* Wv = (const float*)d_in[4];
  const float* Wo = (const float*)d_in[5];
  const float* W1 = (const float*)d_in[6];
  const float* W2 = (const float*)d_in[7];
  const float* ln1g = (const float*)d_in[8];
  const float* ln1b = (const float*)d_in[9];
  const float* ln2g = (const float*)d_in[10];
  const float* ln2b = (const float*)d_in[11];
  float* out = (float*)d_out;

  // workspace layout
  const size_t SLAB = (size_t)BATCH * KCAP * DM;
  char* p = (char*)d_ws;
  int* sidx = (int*)p;                 p += 32768;
  int* partial = (int*)p;              p += (size_t)NSL * BATCH * NTOK * 4;
  float* xb = (float*)p;               p += SLAB * 4;   // persistent token rows (f32)
  ushort* hb = (ushort*)p;             p += SLAB * 2;
  ushort* qh = (ushort*)p;             p += SLAB * 2;
  ushort* Kf = (ushort*)p;             p += SLAB * 2;
  ushort* Vf = (ushort*)p;             p += SLAB * 2;
  ushort* ob = (ushort*)p;             p += SLAB * 2;
  ushort* fb = qh;  // FFN intermediate (13.1MB) overlays qh|Kf|Vf|ob
  ushort* wqt = (ushort*)p;            p += (size_t)4 * 256 * 256 * 2;
  ushort* wkt = (ushort*)p;            p += (size_t)4 * 256 * 256 * 2;
  ushort* wvt = (ushort*)p;            p += (size_t)4 * 256 * 256 * 2;
  ushort* wot = (ushort*)p;            p += (size_t)4 * 256 * 256 * 2;
  ushort* w1t = (ushort*)p;            p += (size_t)4 * 256 * 1024 * 2;
  ushort* w2t = (ushort*)p;            p += (size_t)4 * 1024 * 256 * 2;

  hipMemcpyAsync(out, features, (size_t)BATCH * NTOK * DM * sizeof(float),
                 hipMemcpyDeviceToDevice, stream);
  topk_partial<<<dim3((NTOK + 255) / 256, NSL, BATCH), 256, 0, stream>>>(salience,
                                                                         partial);
  topk_finalize<<<(BATCH * NTOK + 255) / 256, 256, 0, stream>>>(partial, sidx);
  wprep_kernel<<<dim3(512, 1, 6), 256, 0, stream>>>(Wq, Wk, Wv, Wo, W1, W2, wqt,
                                                    wkt, wvt, wot, w1t, w2t);

  const int klens[4] = {3200, 2400, 2000, 1600};
  for (int l = 0; l < 4; ++l) {
    const int klen = klens[l];
    const int nrb = (klen + 31) >> 5;  // 32-row tiles
    const size_t wsq = (size_t)l * 256 * 256;
    const size_t wff = (size_t)l * 256 * 1024;
    if (l == 0) {
      gather_ln_kernel<<<klen / 2, 256, 0, stream>>>(out, sidx, ln1g, ln1b, xb, hb,
                                                     klen);
    } else {
      // nested-prefix top-k: rows of xb persist across layers, no re-gather
      ln_kernel<<<klen / 2, 256, 0, stream>>>(xb, ln1g + l * DM, ln1b + l * DM, hb,
                                              klen);
    }
    qkv_kernel<<<dim3(2 * nrb, 3), 256, 0, stream>>>(
        hb, wqt + wsq, wkt + wsq, wvt + wsq, qh, Kf, Vf, klen);
    attn_kernel<<<dim3(nrb, 8, BATCH), 256, 0, stream>>>(qh, Kf, Vf, ob, klen);
    resadd_kernel<256, 1><<<dim3(2 * nrb, 1), 256, 0, stream>>>(ob, wot + wsq, xb,
                                                                klen);
    ln_kernel<<<klen / 2, 256, 0, stream>>>(xb, ln2g + l * DM, ln2b + l * DM, hb,
                                            klen);
    w1_kernel<<<dim3(2 * nrb, 4), 256, 0, stream>>>(hb, w1t + wff, fb, klen);
    resadd_kernel<1024, 4><<<dim3(2 * nrb, 1), 256, 0, stream>>>(fb, w2t + wff, xb,
                                                                 klen);
  }
  scatter_kernel<<<BATCH * KCAP / 4, 256, 0, stream>>>(xb, sidx, out);
}